// Round 2
// baseline (789.723 us; speedup 1.0000x reference)
//
#include <hip/hip_runtime.h>
#include <hip/hip_bf16.h>

#define IN_F 128
#define HF 256
#define BN_EPS 1e-5f
#define SELU_SCALE 1.0507009873554805f
#define SELU_ALPHA 1.6732632423543772f

typedef __attribute__((ext_vector_type(8))) short short8;
typedef __attribute__((ext_vector_type(4))) short short4v;
typedef __attribute__((ext_vector_type(8))) _Float16 half8;
typedef __attribute__((ext_vector_type(4))) float f32x4;

__device__ __forceinline__ short f2h(float f) {
    _Float16 h = (_Float16)f;               // RTN fp32->fp16
    return __builtin_bit_cast(short, h);
}

__device__ __forceinline__ float selu_f(float x) {
    return SELU_SCALE * (x > 0.f ? x : SELU_ALPHA * expm1f(x));
}

// Fold BN into weights: W'[n][k] = W[n][k]*s[n], b'[n] = (b[n]-m[n])*s[n]+beta[n],
// s = g*rsqrt(v+eps). Store W' as fp16 row-major [n][k] (exactly the LDS B layout:
// lane reads 8 consecutive k for its col n).
__global__ void prep_kernel(const float* __restrict__ W0, const float* __restrict__ b0,
                            const float* __restrict__ g0, const float* __restrict__ beta0,
                            const float* __restrict__ m0, const float* __restrict__ v0,
                            const float* __restrict__ Ws, const float* __restrict__ bs,
                            const float* __restrict__ gs, const float* __restrict__ betas,
                            const float* __restrict__ ms, const float* __restrict__ vs,
                            unsigned short* __restrict__ Wh, float* __restrict__ biasArr) {
    int b = blockIdx.x;
    int layer = b >> 8;
    int n = b & 255;
    int k = threadIdx.x;
    const float *W, *bb, *g, *be, *m, *v;
    if (layer == 0) { W = W0; bb = b0; g = g0; be = beta0; m = m0; v = v0; }
    else {
        int i = layer - 1;
        W = Ws + (size_t)i * HF * HF; bb = bs + i * HF; g = gs + i * HF;
        be = betas + i * HF; m = ms + i * HF; v = vs + i * HF;
    }
    float s = g[n] * rsqrtf(v[n] + BN_EPS);
    Wh[(size_t)layer * HF * HF + n * HF + k] = (unsigned short)f2h(W[n * HF + k] * s);
    if (k == 0) biasArr[layer * HF + n] = (bb[n] - m[n]) * s + be[n];
}

__global__ void count_kernel(const int* __restrict__ dstI, int* __restrict__ cnt, int E) {
    int i = blockIdx.x * 256 + threadIdx.x;
    if (i < E) atomicAdd(cnt + dstI[i], 1);
}

__global__ void finalize_kernel(float* __restrict__ agg, const int* __restrict__ cnt) {
    int n = blockIdx.x;
    float c = fmaxf((float)cnt[n], 1.f);
    agg[(size_t)n * HF + threadIdx.x] = agg[(size_t)n * HF + threadIdx.x] / c;
}

// MODE 0: A = concat(x[dst], x[src]) gathered on the fly (GEMM1)
// MODE 1: A = hbuf rows (GEMM2, in-place)
// MODE 2: MODE 1 + atomic scatter-add of the output into agg[dst[e]] (GEMM3)
// Tile: BM=128, BN=128, BK=64. 4 waves (2x2), each wave a 64x64 output tile
// via 4x4 fragments of mfma_f32_16x16x32_f16. LDS rows padded to 72 halfs
// (144B stride -> 2-way bank aliasing only, which is free).
template <int MODE>
__global__ __launch_bounds__(256)
void gemm_kernel(const float* __restrict__ Asrc,
                 const int* __restrict__ dstI, const int* __restrict__ srcI,
                 const unsigned short* __restrict__ Bg,
                 const float* __restrict__ biasArr,
                 float* __restrict__ hdst, float* __restrict__ agg) {
    __shared__ __align__(16) short As[128 * 72];
    __shared__ __align__(16) short Bs[128 * 72];

    const int bm = blockIdx.x >> 1;
    const int bn = blockIdx.x & 1;
    const int rowBase = bm * 128;
    const int colBase = bn * 128;
    const int t = threadIdx.x;
    const int lane = t & 63;
    const int w = t >> 6;
    const int wr = w >> 1, wc = w & 1;
    const int lrow = lane & 15;
    const int lko = (lane >> 4) * 8;    // k offset within 32-wide K fragment

    f32x4 acc[4][4];
    const f32x4 zero = {0.f, 0.f, 0.f, 0.f};
#pragma unroll
    for (int mi = 0; mi < 4; ++mi)
#pragma unroll
        for (int ni = 0; ni < 4; ++ni) acc[mi][ni] = zero;

#pragma unroll
    for (int kk = 0; kk < 4; ++kk) {
        // ---- stage A: 128 rows x 64 cols, fp32 -> fp16 ----
#pragma unroll
        for (int i = 0; i < 8; ++i) {
            int f = t + i * 256;        // float4 index within tile (0..2047)
            int row = f >> 4;           // 0..127
            int seg = f & 15;           // float4 within row
            const float* src;
            if (MODE == 0) {
                int e = rowBase + row;
                const int* ip = (kk < 2) ? dstI : srcI;   // cols 0-127: x[dst], 128-255: x[src]
                int c0 = (kk & 1) * 64 + seg * 4;
                src = Asrc + (size_t)ip[e] * IN_F + c0;
            } else {
                src = Asrc + (size_t)(rowBase + row) * HF + kk * 64 + seg * 4;
            }
            float4 v = *(const float4*)src;
            short4v bv;
            bv[0] = f2h(v.x); bv[1] = f2h(v.y);
            bv[2] = f2h(v.z); bv[3] = f2h(v.w);
            *(short4v*)&As[row * 72 + seg * 4] = bv;
        }
        // ---- stage B: 128 cols(n) x 64 k, already fp16 [n][k] in global ----
#pragma unroll
        for (int i = 0; i < 4; ++i) {
            int f = t + i * 256;        // ushort8 index (0..1023)
            int n = f >> 3;             // 0..127
            int seg = f & 7;
            *(short8*)&Bs[n * 72 + seg * 8] =
                *(const short8*)(Bg + (size_t)(colBase + n) * HF + kk * 64 + seg * 8);
        }
        __syncthreads();

        half8 afr[4][2], bfr[4][2];
#pragma unroll
        for (int mi = 0; mi < 4; ++mi)
#pragma unroll
            for (int kI = 0; kI < 2; ++kI)
                afr[mi][kI] = *(const half8*)&As[(wr * 64 + mi * 16 + lrow) * 72 + kI * 32 + lko];
#pragma unroll
        for (int ni = 0; ni < 4; ++ni)
#pragma unroll
            for (int kI = 0; kI < 2; ++kI)
                bfr[ni][kI] = *(const half8*)&Bs[(wc * 64 + ni * 16 + lrow) * 72 + kI * 32 + lko];
#pragma unroll
        for (int kI = 0; kI < 2; ++kI)
#pragma unroll
            for (int mi = 0; mi < 4; ++mi)
#pragma unroll
                for (int ni = 0; ni < 4; ++ni)
                    acc[mi][ni] = __builtin_amdgcn_mfma_f32_16x16x32_f16(
                        afr[mi][kI], bfr[ni][kI], acc[mi][ni], 0, 0, 0);
        __syncthreads();
    }

    // ---- epilogue: bias + SELU, write h, optionally atomic scatter ----
#pragma unroll
    for (int mi = 0; mi < 4; ++mi) {
        int growb = rowBase + wr * 64 + mi * 16 + (lane >> 4) * 4;
#pragma unroll
        for (int ni = 0; ni < 4; ++ni) {
            int gcol = colBase + wc * 64 + ni * 16 + (lane & 15);
            float bias = biasArr[gcol];
#pragma unroll
            for (int r = 0; r < 4; ++r) {
                int e = growb + r;
                float val = selu_f(acc[mi][ni][r] + bias);
                hdst[(size_t)e * HF + gcol] = val;
                if (MODE == 2)
                    atomicAdd(agg + (size_t)dstI[e] * HF + gcol, val);
            }
        }
    }
}

extern "C" void kernel_launch(void* const* d_in, const int* in_sizes, int n_in,
                              void* d_out, int out_size, void* d_ws, size_t ws_size,
                              hipStream_t stream) {
    const float* x     = (const float*)d_in[0];
    const int*   ei    = (const int*)d_in[1];
    const float* W0    = (const float*)d_in[2];
    const float* b0    = (const float*)d_in[3];
    const float* g0    = (const float*)d_in[4];
    const float* beta0 = (const float*)d_in[5];
    const float* m0    = (const float*)d_in[6];
    const float* v0    = (const float*)d_in[7];
    const float* Ws    = (const float*)d_in[8];
    const float* bs    = (const float*)d_in[9];
    const float* gs    = (const float*)d_in[10];
    const float* betas = (const float*)d_in[11];
    const float* ms    = (const float*)d_in[12];
    const float* vs    = (const float*)d_in[13];

    const int Nn = in_sizes[0] / IN_F;   // 20000
    const int E  = in_sizes[1] / 2;      // 320000

    float* agg  = (float*)d_out;
    float* hbuf = agg + (size_t)Nn * HF;   // h region of d_out, also used for intermediates

    // workspace: [0, 384K) fp16 folded weights; [384K, +3K) folded biases; then counts
    unsigned short* Wh = (unsigned short*)d_ws;
    float* biasArr = (float*)((char*)d_ws + 3 * HF * HF * sizeof(unsigned short));
    int* cnt = (int*)((char*)d_ws + 3 * HF * HF * sizeof(unsigned short) + 3 * HF * sizeof(float));

    const int* srcI = ei;        // edge_index[0]
    const int* dstI = ei + E;    // edge_index[1]

    hipMemsetAsync(d_out, 0, (size_t)Nn * HF * sizeof(float), stream);  // agg accum
    hipMemsetAsync(cnt, 0, (size_t)Nn * sizeof(int), stream);

    prep_kernel<<<3 * HF, HF, 0, stream>>>(W0, b0, g0, beta0, m0, v0,
                                           Ws, bs, gs, betas, ms, vs, Wh, biasArr);
    count_kernel<<<(E + 255) / 256, 256, 0, stream>>>(dstI, cnt, E);

    const int grid = (E / 128) * 2;   // 2500 row-blocks x 2 col-blocks
    gemm_kernel<0><<<grid, 256, 0, stream>>>(x,    dstI, srcI, Wh,               biasArr,       hbuf, nullptr);
    gemm_kernel<1><<<grid, 256, 0, stream>>>(hbuf, dstI, srcI, Wh + HF * HF,     biasArr + HF,  hbuf, nullptr);
    gemm_kernel<2><<<grid, 256, 0, stream>>>(hbuf, dstI, srcI, Wh + 2 * HF * HF, biasArr + 2 * HF, hbuf, agg);

    finalize_kernel<<<Nn, HF, 0, stream>>>(agg, cnt);
}